// Round 13
// baseline (152.800 us; speedup 1.0000x reference)
//
#include <hip/hip_runtime.h>
#include <hip/hip_cooperative_groups.h>
#include <math.h>

namespace cg = cooperative_groups;

#define B_    2
#define HC_   96
#define WC_   96
#define HF_   384
#define WF_   384
#define CINC_ 256
#define CH_   64
#define COUT_ 19

typedef __attribute__((ext_vector_type(8))) short bf16x8;
typedef __attribute__((ext_vector_type(4))) float f32x4;

__device__ __forceinline__ unsigned short f2bf(float f) {
    unsigned int u = __float_as_uint(f);
    u += 0x7fffu + ((u >> 16) & 1u);
    return (unsigned short)(u >> 16);
}
__device__ __forceinline__ unsigned int pk2(float a, float b) {
    return (unsigned int)f2bf(a) | ((unsigned int)f2bf(b) << 16);
}
__device__ __forceinline__ float bflo(unsigned int u) { return __uint_as_float(u << 16); }
__device__ __forceinline__ float bfhi(unsigned int u) { return __uint_as_float(u & 0xffff0000u); }

__device__ __forceinline__ void gl_lds16(const void* g, void* l) {
    __builtin_amdgcn_global_load_lds(
        (const __attribute__((address_space(1))) void*)g,
        (__attribute__((address_space(3))) void*)l, 16, 0, 0);
}

// Xt layout: [b][chunk32 = ck*4 + part][9604 halo px][8 ch] bf16 (uint4 granules)
#define XT_IDX(b, chunk, hpx)  (((size_t)((b) * 32 + (chunk))) * 9604 + (hpx))

// ===================== shared phase bodies (device functions) =====================

__device__ __forceinline__ void phaseP_body(
    int w, int tid,
    const float* __restrict__ coarse,
    const float* __restrict__ w_ec, const float* __restrict__ w_v,
    const float* __restrict__ w_q,  const float* __restrict__ b_q,
    const float* __restrict__ b_v,
    uint4* __restrict__ Xt4,
    unsigned short* __restrict__ A_pk, unsigned short* __restrict__ Avc,
    float* __restrict__ drv)
{
    if (w < 576) {
        int i = w * 256 + tid;
        {
            int e = i & 7, l = (i >> 3) & 63, m = (i >> 9) & 3, ck = (i >> 11) & 7, tap = i >> 14;
            int oc = m * 16 + (l & 15);
            int ch = ck * 32 + (l >> 4) * 8 + e;
            A_pk[i] = f2bf(w_ec[(oc * 256 + ch) * 9 + tap]);
        }
        if (i < 8192) {
            int e = i & 7, l = (i >> 3) & 63, m = (i >> 9) & 1, ck = (i >> 10) & 7;
            int ov = m * 16 + (l & 15);
            int ch = ck * 32 + (l >> 4) * 8 + e;
            Avc[i] = (ov < COUT_) ? f2bf(w_v[ov * 320 + ch]) : (unsigned short)0;
        }
    } else if (w < 580) {
        int e = (w - 576) * 256 + tid;
        if (e < 388 * B_) {
            int b = e / 388, i = e - b * 388;
            int gy, gx;
            if (i < 98)       { gy = 0;           gx = i; }
            else if (i < 196) { gy = 97;          gx = i - 98; }
            else if (i < 292) { gy = i - 196 + 1; gx = 0; }
            else              { gy = i - 292 + 1; gx = 97; }
            const int hpx = gy * 98 + gx;
            uint4 zz; zz.x = zz.y = zz.z = zz.w = 0u;
            #pragma unroll
            for (int c = 0; c < 32; ++c) Xt4[XT_IDX(b, c, hpx)] = zz;
        }
    } else if (w < 1156) {
        int u = w - 580;                   // 0..575
        int bx = u % 36;
        int v2 = u / 36;                   // 0..15
        int cg2 = v2 & 7;
        int b  = v2 >> 3;
        int px = bx * 256 + tid;           // 0..9215
        int gy = px / 96, gx = px - gy * 96;
        const int hpx = (gy + 1) * 98 + gx + 1;
        const float* src = coarse + (size_t)b * CINC_ * 9216 + px;
        #pragma unroll
        for (int cc = 0; cc < 4; ++cc) {
            const int chunk = cg2 * 4 + cc;
            float f[8];
            #pragma unroll
            for (int t = 0; t < 8; ++t) f[t] = src[(size_t)(chunk * 8 + t) * 9216];
            uint4 v;
            v.x = pk2(f[0], f[1]);
            v.y = pk2(f[2], f[3]);
            v.z = pk2(f[4], f[5]);
            v.w = pk2(f[6], f[7]);
            Xt4[XT_IDX(b, chunk, hpx)] = v;
        }
    } else {
        int i = tid;
        if (i < 9) {
            int ci = i / 3, cj = i % 3;
            float a = 0.f;
            for (int c = 0; c < 64; ++c) a += w_q[c * 3 + ci] * w_q[c * 3 + cj];
            drv[i] = a;
        } else if (i < 12) {
            int ci = i - 9;
            float a = 0.f;
            for (int c = 0; c < 64; ++c) a += w_q[c * 3 + ci] * b_q[c];
            drv[i] = a;
        } else if (i == 12) {
            float a = 0.f;
            for (int c = 0; c < 64; ++c) a += b_q[c] * b_q[c];
            drv[12] = a;
        } else if (i < 70) {
            int idx = i - 13, ci = idx / 19, ov = idx % 19;
            float a = 0.f;
            for (int c = 0; c < 64; ++c) a += w_v[ov * 320 + 256 + c] * w_q[c * 3 + ci];
            drv[i] = a;
        } else if (i < 89) {
            int ov = i - 70;
            float a = b_v[ov];
            for (int c = 0; c < 64; ++c) a += w_v[ov * 320 + 256 + c] * b_q[c];
            drv[i] = a;
        }
    }
}

// Phase E body: one (tile, z) work item. sB is the 48KB 4-buffer LDS.
__device__ __forceinline__ void phaseE_body(
    int w, int tid, uint4 (*sB)[768],
    const uint4* __restrict__ Xt4,
    const unsigned short* __restrict__ A_pk,
    const unsigned short* __restrict__ Avc,
    const float* __restrict__ b_ec, const float* __restrict__ w_eh,
    float* __restrict__ eh4, unsigned short* __restrict__ cvb)
{
    const int lane = tid & 63;
    const int wv   = tid >> 6;
    const int j    = lane & 15;
    const int g    = lane >> 4;

    const int xcd  = w & 7;
    const int sl0  = w >> 3;
    const int z    = sl0 & 3;
    const int t8   = sl0 >> 2;
    const int tile = t8 * 8 + xcd;
    const int b    = tile / 72;
    const int tl   = tile - b * 72;
    const int ty0  = (tl / 6) * 8;
    const int tx0  = (tl % 6) * 16;

    f32x4 acc0 = (f32x4)0.f, acc1 = (f32x4)0.f;
    f32x4 accv[2][2];
    accv[0][0] = accv[0][1] = accv[1][0] = accv[1][1] = (f32x4)0.f;

    const bf16x8* Af  = (const bf16x8*)A_pk;
    const bf16x8* Avf = (const bf16x8*)Avc;

#define STAGE_EC(BUF, CK)                                                      \
    {                                                                          \
        _Pragma("unroll")                                                      \
        for (int rr = 0; rr < 3; ++rr) {                                       \
            int slot = 192 * wv + 64 * rr + lane;                              \
            int px = slot >> 2;                                                \
            px = px > 179 ? 179 : px;                                          \
            int part = (slot & 3) ^ ((px >> 1) & 3);                           \
            int row = px / 18, col = px - row * 18;                            \
            const uint4* src = Xt4 + XT_IDX(b, (CK) * 4 + part,                \
                                            (ty0 + row) * 98 + (tx0 + col));   \
            gl_lds16(src, &sB[BUF][192 * wv + 64 * rr]);                       \
        }                                                                      \
    }

    STAGE_EC(0, 0);
    STAGE_EC(1, 1);

    #pragma unroll
    for (int ck = 0; ck < 8; ++ck) {
        if (ck < 6) STAGE_EC((ck + 2) & 3, ck + 2);

        if (ck < 6)       asm volatile("s_waitcnt vmcnt(6)" ::: "memory");
        else if (ck == 6) asm volatile("s_waitcnt vmcnt(3)" ::: "memory");
        else              asm volatile("s_waitcnt vmcnt(0)" ::: "memory");
        __builtin_amdgcn_sched_barrier(0);
        asm volatile("s_barrier" ::: "memory");

        const int cur = ck & 3;
        bf16x8 frg[4][3];
        #pragma unroll
        for (int rr = 0; rr < 4; ++rr)
            #pragma unroll
            for (int dx = 0; dx < 3; ++dx) {
                int px = (2 * wv + rr) * 18 + j + dx;
                int slot = (px << 2) + (g ^ ((px >> 1) & 3));
                frg[rr][dx] = *(const bf16x8*)&sB[cur][slot];
            }

        #pragma unroll
        for (int tap = 0; tap < 9; ++tap) {
            const int dy = tap / 3, dx = tap % 3;
            bf16x8 a = Af[((tap * 8 + ck) * 4 + z) * 64 + lane];
            acc0 = __builtin_amdgcn_mfma_f32_16x16x32_bf16(a, frg[dy][dx], acc0, 0, 0, 0);
            acc1 = __builtin_amdgcn_mfma_f32_16x16x32_bf16(a, frg[dy + 1][dx], acc1, 0, 0, 0);
        }
        if (z == 0) {
            bf16x8 av0 = Avf[(ck * 2 + 0) * 64 + lane];
            bf16x8 av1 = Avf[(ck * 2 + 1) * 64 + lane];
            accv[0][0] = __builtin_amdgcn_mfma_f32_16x16x32_bf16(av0, frg[1][1], accv[0][0], 0, 0, 0);
            accv[0][1] = __builtin_amdgcn_mfma_f32_16x16x32_bf16(av0, frg[2][1], accv[0][1], 0, 0, 0);
            accv[1][0] = __builtin_amdgcn_mfma_f32_16x16x32_bf16(av1, frg[1][1], accv[1][0], 0, 0, 0);
            accv[1][1] = __builtin_amdgcn_mfma_f32_16x16x32_bf16(av1, frg[2][1], accv[1][1], 0, 0, 0);
        }
    }
#undef STAGE_EC

    float we[4], be[4];
    #pragma unroll
    for (int q = 0; q < 4; ++q) {
        int oc = z * 16 + 4 * g + q;
        we[q] = w_eh[oc];
        be[q] = b_ec[oc];
    }
    #pragma unroll
    for (int r = 0; r < 2; ++r) {
        const f32x4 accr = r ? acc1 : acc0;
        float p = 0.f;
        #pragma unroll
        for (int q = 0; q < 4; ++q)
            p += we[q] * fmaxf(accr[q] + be[q], 0.f);
        p += __shfl_xor(p, 16);
        p += __shfl_xor(p, 32);
        const int gpix = (ty0 + 2 * wv + r) * WC_ + tx0 + j;
        if (g == 0)
            eh4[((size_t)b * (HC_ * WC_) + gpix) * 4 + z] = p;
        if (z == 0) {
            unsigned short* cvp = cvb + ((size_t)b * (HC_ * WC_) + gpix) * 24;
            #pragma unroll
            for (int m = 0; m < 2; ++m)
                #pragma unroll
                for (int q = 0; q < 4; ++q) {
                    int ov = m * 16 + 4 * g + q;
                    if (ov < 20) cvp[ov] = f2bf(accv[m][r][q]);
                }
        }
    }
}

struct FineSmem {
    float sRaw[3][20][20];
    unsigned short sV[324 * 26];
    float sNE[324];
};

__device__ __forceinline__ void phaseF_body(
    int w, int tid, FineSmem* f,
    const float* __restrict__ raw,
    const float* __restrict__ w_ef, const float* __restrict__ b_ef,
    const float* __restrict__ w_eh, const float* __restrict__ drv,
    const float* __restrict__ eh4, const unsigned short* __restrict__ cvb,
    float* __restrict__ out_y, float* __restrict__ out_ne)
{
    const int bx = w % 24;
    const int by = (w / 24) % 24;
    const int b  = w / 576;
    const int ty0 = by * 16;
    const int tx0 = bx * 16;
    const float* rb = raw + (size_t)b * 3 * (HF_ * WF_);

    const float* Gm = drv;
    const float* uv = drv + 9;
    const float* Mm = drv + 13;
    const float* bc = drv + 70;

    for (int i = tid; i < 1200; i += 256) {
        int ch = i / 400, rem = i - ch * 400;
        int ry = rem / 20, rx = rem - ry * 20;
        int gh = ty0 + ry - 2, gw = tx0 + rx - 2;
        float v = 0.f;
        if (gh >= 0 && gh < HF_ && gw >= 0 && gw < WF_)
            v = rb[(size_t)ch * (HF_ * WF_) + gh * WF_ + gw];
        f->sRaw[ch][ry][rx] = v;
    }
    __syncthreads();

    for (int p = tid; p < 324; p += 256) {
        const int iy = p / 18, ix = p - iy * 18;
        const int gh = ty0 + iy - 1, gw = tx0 + ix - 1;
        unsigned int* vw = (unsigned int*)&f->sV[p * 26];
        if (gh < 0 || gh >= HF_ || gw < 0 || gw >= WF_) {
            #pragma unroll
            for (int q = 0; q < 10; ++q) vw[q] = 0u;
            f->sNE[p] = 0.f;
            continue;
        }
        float ef = b_ef[0];
        #pragma unroll
        for (int ci = 0; ci < 3; ++ci)
            #pragma unroll
            for (int t = 0; t < 9; ++t)
                ef = fmaf(w_ef[ci * 9 + t], f->sRaw[ci][iy + t / 3][ix + t % 3], ef);
        ef = fmaxf(ef, 0.f);

        const int cpix = (gh >> 2) * WC_ + (gw >> 2);
        const float4 ehv = *(const float4*)(eh4 + ((size_t)b * (HC_ * WC_) + cpix) * 4);
        float logit = fmaf(w_eh[64], ef, (ehv.x + ehv.y) + (ehv.z + ehv.w));
        float ne = 1.f / (1.f + __expf(-logit));
        f->sNE[p] = ne;

        const float r0 = f->sRaw[0][iy + 1][ix + 1];
        const float r1 = f->sRaw[1][iy + 1][ix + 1];
        const float r2 = f->sRaw[2][iy + 1][ix + 1];

        float v[20];
        {
            const uint4* cvp = (const uint4*)(cvb + ((size_t)b * (HC_ * WC_) + cpix) * 24);
            uint4 a0 = cvp[0], a1 = cvp[1], a2 = cvp[2];
            unsigned int w10[10] = {a0.x, a0.y, a0.z, a0.w, a1.x, a1.y, a1.z, a1.w, a2.x, a2.y};
            #pragma unroll
            for (int o2 = 0; o2 < 10; ++o2) {
                v[2 * o2]     = bflo(w10[o2]);
                v[2 * o2 + 1] = bfhi(w10[o2]);
            }
        }
        #pragma unroll
        for (int ov = 0; ov < COUT_; ++ov)
            v[ov] = fmaf(Mm[38 + ov], r2,
                    fmaf(Mm[19 + ov], r1,
                    fmaf(Mm[ov], r0, v[ov] + bc[ov])));

        #pragma unroll
        for (int o2 = 0; o2 < 9; ++o2)
            vw[o2] = pk2(v[2 * o2], v[2 * o2 + 1]);
        vw[9] = (unsigned int)f2bf(v[18]);
    }
    __syncthreads();

    const int py = tid >> 4, px2 = tid & 15;
    const int iy = py + 1, ix = px2 + 1;
    const int pbase = iy * 18 + ix;

    float rn[3][9];
    #pragma unroll
    for (int ci = 0; ci < 3; ++ci)
        #pragma unroll
        for (int k = 0; k < 9; ++k)
            rn[ci][k] = f->sRaw[ci][iy + k / 3][ix + k % 3];

    const float rc0 = rn[0][4], rc1 = rn[1][4], rc2 = rn[2][4];
    const float h0 = fmaf(Gm[0], rc0, fmaf(Gm[1], rc1, fmaf(Gm[2], rc2, uv[0])));
    const float h1 = fmaf(Gm[3], rc0, fmaf(Gm[4], rc1, fmaf(Gm[5], rc2, uv[1])));
    const float h2 = fmaf(Gm[6], rc0, fmaf(Gm[7], rc1, fmaf(Gm[8], rc2, uv[2])));
    const float ac = fmaf(uv[0], rc0, fmaf(uv[1], rc1, fmaf(uv[2], rc2, drv[12])));

    float sc[9];
    #pragma unroll
    for (int k = 0; k < 9; ++k) {
        float d = fmaf(h0, rn[0][k], fmaf(h1, rn[1][k], fmaf(h2, rn[2][k], ac)));
        const int pn = pbase + (k / 3 - 1) * 18 + (k % 3 - 1);
        sc[k] = f->sNE[pn] * d;
    }
    float mmax = sc[0];
    #pragma unroll
    for (int k = 1; k < 9; ++k) mmax = fmaxf(mmax, sc[k]);
    float e[9];
    float ssum = 0.f;
    #pragma unroll
    for (int k = 0; k < 9; ++k) { e[k] = __expf(sc[k] - mmax); ssum += e[k]; }
    const float inv = 1.f / ssum;

    float y[COUT_];
    #pragma unroll
    for (int ov = 0; ov < COUT_; ++ov) y[ov] = 0.f;
    #pragma unroll
    for (int k = 0; k < 9; ++k) {
        const int pn = pbase + (k / 3 - 1) * 18 + (k % 3 - 1);
        const float a = e[k] * inv;
        const unsigned int* vp = (const unsigned int*)&f->sV[pn * 26];
        #pragma unroll
        for (int o2 = 0; o2 < 9; ++o2) {
            unsigned int u = vp[o2];
            y[2 * o2]     = fmaf(a, bflo(u), y[2 * o2]);
            y[2 * o2 + 1] = fmaf(a, bfhi(u), y[2 * o2 + 1]);
        }
        y[18] = fmaf(a, bflo(vp[9]), y[18]);
    }

    const int gh = ty0 + py, gw = tx0 + px2;
    const size_t ppos = (size_t)gh * WF_ + gw;
    #pragma unroll
    for (int ov = 0; ov < COUT_; ++ov)
        out_y[((size_t)b * COUT_ + ov) * (HF_ * WF_) + ppos] = y[ov];
    out_ne[(size_t)b * (HF_ * WF_) + ppos] = f->sNE[pbase];
}

// ===================== fused cooperative kernel =====================
__global__ __launch_bounds__(256, 2) void k_all(
    const float* __restrict__ coarse, const float* __restrict__ raw,
    const float* __restrict__ w_ef,   const float* __restrict__ b_ef,
    const float* __restrict__ w_ec,   const float* __restrict__ b_ec,
    const float* __restrict__ w_eh,
    const float* __restrict__ w_q,    const float* __restrict__ b_q,
    const float* __restrict__ w_v,    const float* __restrict__ b_v,
    uint4* __restrict__ Xt4,
    unsigned short* __restrict__ A_pk, unsigned short* __restrict__ Avc,
    float* __restrict__ eh4, unsigned short* __restrict__ cvb,
    float* __restrict__ drv,
    float* __restrict__ out_y, float* __restrict__ out_ne)
{
    __shared__ union {
        uint4 sB[4][768];     // 48 KB (phase E)
        FineSmem f;           // ~23 KB (phase F)
    } sm;

    const int bid = blockIdx.x;
    const int gsz = gridDim.x;
    const int tid = threadIdx.x;

    for (int w = bid; w < 1157; w += gsz)
        phaseP_body(w, tid, coarse, w_ec, w_v, w_q, b_q, b_v, Xt4, A_pk, Avc, drv);

    cg::this_grid().sync();

    for (int w = bid; w < 576; w += gsz) {
        phaseE_body(w, tid, sm.sB, Xt4, A_pk, Avc, b_ec, w_eh, eh4, cvb);
        __syncthreads();
    }

    cg::this_grid().sync();

    for (int w = bid; w < 1152; w += gsz) {
        __syncthreads();
        phaseF_body(w, tid, &sm.f, raw, w_ef, b_ef, w_eh, drv, eh4, cvb, out_y, out_ne);
    }
}

// ===================== fallback 3-kernel path (R11, proven) =====================
__global__ __launch_bounds__(256) void k_pre(
    const float* __restrict__ x,
    const float* __restrict__ w_ec, const float* __restrict__ w_v,
    const float* __restrict__ w_q,  const float* __restrict__ b_q,
    const float* __restrict__ b_v,
    uint4* __restrict__ Xt4,
    unsigned short* __restrict__ A_pk, unsigned short* __restrict__ Avc,
    float* __restrict__ drv)
{
    phaseP_body(blockIdx.x, threadIdx.x, x, w_ec, w_v, w_q, b_q, b_v, Xt4, A_pk, Avc, drv);
}

__global__ __launch_bounds__(256, 2) void k_ec(
    const uint4* __restrict__ Xt4,
    const unsigned short* __restrict__ A_pk,
    const unsigned short* __restrict__ Avc,
    const float* __restrict__ b_ec, const float* __restrict__ w_eh,
    float* __restrict__ eh4, unsigned short* __restrict__ cvb)
{
    __shared__ uint4 sB[4][768];
    phaseE_body(blockIdx.x, threadIdx.x, sB, Xt4, A_pk, Avc, b_ec, w_eh, eh4, cvb);
}

__global__ __launch_bounds__(256) void k_fine(
    const float* __restrict__ raw,
    const float* __restrict__ w_ef, const float* __restrict__ b_ef,
    const float* __restrict__ w_eh, const float* __restrict__ drv,
    const float* __restrict__ eh4, const unsigned short* __restrict__ cvb,
    float* __restrict__ out_y, float* __restrict__ out_ne)
{
    __shared__ FineSmem f;
    phaseF_body(blockIdx.x, threadIdx.x, &f, raw, w_ef, b_ef, w_eh, drv, eh4, cvb, out_y, out_ne);
}

// ---------------- launch ----------------
extern "C" void kernel_launch(void* const* d_in, const int* in_sizes, int n_in,
                              void* d_out, int out_size, void* d_ws, size_t ws_size,
                              hipStream_t stream)
{
    const float* coarse = (const float*)d_in[0];
    const float* raw    = (const float*)d_in[1];
    const float* w_ef   = (const float*)d_in[2];
    const float* b_ef   = (const float*)d_in[3];
    const float* w_ec   = (const float*)d_in[4];
    const float* b_ec   = (const float*)d_in[5];
    const float* w_eh   = (const float*)d_in[6];
    const float* w_q    = (const float*)d_in[7];
    const float* b_q    = (const float*)d_in[8];
    const float* w_v    = (const float*)d_in[9];
    const float* b_v    = (const float*)d_in[10];
    (void)in_sizes; (void)n_in; (void)out_size; (void)ws_size;

    unsigned char* ws = (unsigned char*)d_ws;
    size_t off = 0;
    uint4* Xt4            = (uint4*)(ws + off);          off += (size_t)B_ * 32 * 9604 * 16;
    unsigned short* A_pk  = (unsigned short*)(ws + off); off += 294912;
    unsigned short* Avc   = (unsigned short*)(ws + off); off += 16384;
    float* eh4            = (float*)(ws + off);          off += (size_t)B_ * 9216 * 4 * 4;
    unsigned short* cvb   = (unsigned short*)(ws + off); off += (size_t)B_ * 9216 * 24 * 2;
    float* drv            = (float*)(ws + off);          off += 512;

    float* out_y  = (float*)d_out;
    float* out_ne = out_y + (size_t)B_ * COUT_ * HF_ * WF_;

    // size cooperative grid from the runtime's own occupancy calc
    int maxPerCU = 0;
    hipError_t occ = hipOccupancyMaxActiveBlocksPerMultiprocessor(
        &maxPerCU, (const void*)k_all, 256, 0);
    int grid = 512;
    if (occ == hipSuccess && maxPerCU >= 1) {
        grid = maxPerCU * 256;
        if (grid > 1152) grid = 1152;
        if (grid < 256)  grid = 256;
    }

    void* args[] = {
        (void*)&coarse, (void*)&raw, (void*)&w_ef, (void*)&b_ef, (void*)&w_ec,
        (void*)&b_ec,   (void*)&w_eh, (void*)&w_q, (void*)&b_q,  (void*)&w_v,
        (void*)&b_v,    (void*)&Xt4,  (void*)&A_pk, (void*)&Avc, (void*)&eh4,
        (void*)&cvb,    (void*)&drv,  (void*)&out_y, (void*)&out_ne
    };
    hipError_t e = hipLaunchCooperativeKernel((void*)k_all, dim3(grid), dim3(256),
                                              args, 0, stream);
    if (e != hipSuccess) {
        // proven 3-kernel fallback (R11 numerics, identical outputs)
        hipLaunchKernelGGL(k_pre, dim3(1157), dim3(256), 0, stream,
                           coarse, w_ec, w_v, w_q, b_q, b_v, Xt4, A_pk, Avc, drv);
        hipLaunchKernelGGL(k_ec, dim3(576), dim3(256), 0, stream,
                           Xt4, A_pk, Avc, b_ec, w_eh, eh4, cvb);
        hipLaunchKernelGGL(k_fine, dim3(1152), dim3(256), 0, stream,
                           raw, w_ef, b_ef, w_eh, drv, eh4, cvb, out_y, out_ne);
    }
}

// Round 14
// 44.211 us; speedup vs baseline: 3.4561x; 3.4561x over previous
//
#include <hip/hip_runtime.h>
#include <math.h>

#define B_    2
#define HC_   96
#define WC_   96
#define HF_   384
#define WF_   384
#define CINC_ 256
#define CH_   64
#define COUT_ 19

typedef __attribute__((ext_vector_type(8))) short bf16x8;
typedef __attribute__((ext_vector_type(4))) float f32x4;

__device__ __forceinline__ unsigned short f2bf(float f) {
    unsigned int u = __float_as_uint(f);
    u += 0x7fffu + ((u >> 16) & 1u);
    return (unsigned short)(u >> 16);
}
__device__ __forceinline__ unsigned int pk2(float a, float b) {
    return (unsigned int)f2bf(a) | ((unsigned int)f2bf(b) << 16);
}
__device__ __forceinline__ float bflo(unsigned int u) { return __uint_as_float(u << 16); }
__device__ __forceinline__ float bfhi(unsigned int u) { return __uint_as_float(u & 0xffff0000u); }

__device__ __forceinline__ void gl_lds16(const void* g, void* l) {
    __builtin_amdgcn_global_load_lds(
        (const __attribute__((address_space(1))) void*)g,
        (__attribute__((address_space(3))) void*)l, 16, 0, 0);
}

// Xt layout: [b][chunk32 = ck*4 + part][9604 halo px][8 ch] bf16 (uint4 granules)
#define XT_IDX(b, chunk, hpx)  (((size_t)((b) * 32 + (chunk))) * 9604 + (hpx))

// ---------------- K_pre ----------------
// bid 0-575   : weight prep (A_pk, Avc)
// bid 576-579 : zero 1-px border of Xt (all 32 chunks)
// bid 580-1155: transpose coarse f32 -> Xt (interior), 4 chunks/block
// bid 1156    : derived weights drv[89]
__global__ __launch_bounds__(256) void k_pre(
    const float* __restrict__ x,      // coarse
    const float* __restrict__ w_ec, const float* __restrict__ w_v,
    const float* __restrict__ w_q,  const float* __restrict__ b_q,
    const float* __restrict__ b_v,
    uint4* __restrict__ Xt4,
    unsigned short* __restrict__ A_pk, unsigned short* __restrict__ Avc,
    float* __restrict__ drv)
{
    const int bid = blockIdx.x;
    const int tid = threadIdx.x;
    if (bid < 576) {
        int i = bid * 256 + tid;
        {
            int e = i & 7, l = (i >> 3) & 63, m = (i >> 9) & 3, ck = (i >> 11) & 7, tap = i >> 14;
            int oc = m * 16 + (l & 15);
            int ch = ck * 32 + (l >> 4) * 8 + e;
            A_pk[i] = f2bf(w_ec[(oc * 256 + ch) * 9 + tap]);
        }
        if (i < 8192) {
            int e = i & 7, l = (i >> 3) & 63, m = (i >> 9) & 1, ck = (i >> 10) & 7;
            int ov = m * 16 + (l & 15);
            int ch = ck * 32 + (l >> 4) * 8 + e;
            Avc[i] = (ov < COUT_) ? f2bf(w_v[ov * 320 + ch]) : (unsigned short)0;
        }
        return;
    }
    if (bid < 580) {
        int e = (bid - 576) * 256 + tid;
        if (e >= 388 * B_) return;
        int b = e / 388, i = e - b * 388;
        int gy, gx;
        if (i < 98)       { gy = 0;           gx = i; }
        else if (i < 196) { gy = 97;          gx = i - 98; }
        else if (i < 292) { gy = i - 196 + 1; gx = 0; }
        else              { gy = i - 292 + 1; gx = 97; }
        const int hpx = gy * 98 + gx;
        uint4 zz; zz.x = zz.y = zz.z = zz.w = 0u;
        #pragma unroll
        for (int c = 0; c < 32; ++c) Xt4[XT_IDX(b, c, hpx)] = zz;
        return;
    }
    if (bid < 1156) {
        int u = bid - 580;                 // 0..575
        int bx = u % 36;
        int v2 = u / 36;                   // 0..15
        int cg = v2 & 7;                   // chunk group (4 chunks each)
        int b  = v2 >> 3;
        int px = bx * 256 + tid;           // 0..9215
        int gy = px / 96, gx = px - gy * 96;
        const int hpx = (gy + 1) * 98 + gx + 1;
        const float* src = x + (size_t)b * CINC_ * 9216 + px;
        #pragma unroll
        for (int cc = 0; cc < 4; ++cc) {
            const int chunk = cg * 4 + cc;
            float f[8];
            #pragma unroll
            for (int t = 0; t < 8; ++t) f[t] = src[(size_t)(chunk * 8 + t) * 9216];
            uint4 v;
            v.x = pk2(f[0], f[1]);
            v.y = pk2(f[2], f[3]);
            v.z = pk2(f[4], f[5]);
            v.w = pk2(f[6], f[7]);
            Xt4[XT_IDX(b, chunk, hpx)] = v;   // coalesced: lanes -> consecutive px
        }
        return;
    }
    // derived weights
    {
        int i = tid;
        if (i < 9) {
            int ci = i / 3, cj = i % 3;
            float a = 0.f;
            for (int c = 0; c < 64; ++c) a += w_q[c * 3 + ci] * w_q[c * 3 + cj];
            drv[i] = a;
        } else if (i < 12) {
            int ci = i - 9;
            float a = 0.f;
            for (int c = 0; c < 64; ++c) a += w_q[c * 3 + ci] * b_q[c];
            drv[i] = a;
        } else if (i == 12) {
            float a = 0.f;
            for (int c = 0; c < 64; ++c) a += b_q[c] * b_q[c];
            drv[12] = a;
        } else if (i < 70) {
            int idx = i - 13, ci = idx / 19, ov = idx % 19;
            float a = 0.f;
            for (int c = 0; c < 64; ++c) a += w_v[ov * 320 + 256 + c] * w_q[c * 3 + ci];
            drv[i] = a;
        } else if (i < 89) {
            int ov = i - 70;
            float a = b_v[ov];
            for (int c = 0; c < 64; ++c) a += w_v[ov * 320 + 256 + c] * b_q[c];
            drv[i] = a;
        }
        return;
    }
}

// ---------------- K_ec: MFMA conv3x3 (16 oc quarter) + cv GEMM (z==0) ---------------
// 1D grid 576, XCD-affinity decode. T3/T4 pipeline: 4 LDS bufs, depth-2 prefetch,
// counted vmcnt + raw s_barrier (never drain-0 in loop).
__global__ __launch_bounds__(256, 2) void k_ec(
    const uint4* __restrict__ Xt4,
    const unsigned short* __restrict__ A_pk,
    const unsigned short* __restrict__ Avc,
    const float* __restrict__ b_ec, const float* __restrict__ w_eh,
    float* __restrict__ eh4,             // (B,9216,4) f32
    unsigned short* __restrict__ cvb)    // (B,9216,24) bf16
{
    __shared__ uint4 sB[4][768];   // 4 x 12 KB; slots [px*4 + swz(part)]

    const int tid  = threadIdx.x;
    const int lane = tid & 63;
    const int wv   = tid >> 6;
    const int j    = lane & 15;
    const int g    = lane >> 4;

    const int flat = blockIdx.x;          // 0..575
    const int xcd  = flat & 7;
    const int slot0 = flat >> 3;          // 0..71
    const int z    = slot0 & 3;
    const int t8   = slot0 >> 2;          // 0..17
    const int tile = t8 * 8 + xcd;        // 0..143
    const int b    = tile / 72;
    const int tl   = tile - b * 72;
    const int ty0  = (tl / 6) * 8;
    const int tx0  = (tl % 6) * 16;

    f32x4 acc0 = (f32x4)0.f, acc1 = (f32x4)0.f;
    f32x4 accv[2][2];
    accv[0][0] = accv[0][1] = accv[1][0] = accv[1][1] = (f32x4)0.f;

    const bf16x8* Af  = (const bf16x8*)A_pk;
    const bf16x8* Avf = (const bf16x8*)Avc;

#define STAGE_EC(BUF, CK)                                                      \
    {                                                                          \
        _Pragma("unroll")                                                      \
        for (int rr = 0; rr < 3; ++rr) {                                       \
            int slot = 192 * wv + 64 * rr + lane;                              \
            int px = slot >> 2;                                                \
            px = px > 179 ? 179 : px;                                          \
            int part = (slot & 3) ^ ((px >> 1) & 3);                           \
            int row = px / 18, col = px - row * 18;                            \
            const uint4* src = Xt4 + XT_IDX(b, (CK) * 4 + part,                \
                                            (ty0 + row) * 98 + (tx0 + col));   \
            gl_lds16(src, &sB[BUF][192 * wv + 64 * rr]);                       \
        }                                                                      \
    }

    STAGE_EC(0, 0);
    STAGE_EC(1, 1);

    #pragma unroll
    for (int ck = 0; ck < 8; ++ck) {
        if (ck < 6) STAGE_EC((ck + 2) & 3, ck + 2);

        if (ck < 6)       asm volatile("s_waitcnt vmcnt(6)" ::: "memory");
        else if (ck == 6) asm volatile("s_waitcnt vmcnt(3)" ::: "memory");
        else              asm volatile("s_waitcnt vmcnt(0)" ::: "memory");
        __builtin_amdgcn_sched_barrier(0);
        asm volatile("s_barrier" ::: "memory");

        const int cur = ck & 3;
        bf16x8 frg[4][3];
        #pragma unroll
        for (int rr = 0; rr < 4; ++rr)
            #pragma unroll
            for (int dx = 0; dx < 3; ++dx) {
                int px = (2 * wv + rr) * 18 + j + dx;
                int slot = (px << 2) + (g ^ ((px >> 1) & 3));
                frg[rr][dx] = *(const bf16x8*)&sB[cur][slot];
            }

        #pragma unroll
        for (int tap = 0; tap < 9; ++tap) {
            const int dy = tap / 3, dx = tap % 3;
            bf16x8 a = Af[((tap * 8 + ck) * 4 + z) * 64 + lane];
            acc0 = __builtin_amdgcn_mfma_f32_16x16x32_bf16(a, frg[dy][dx], acc0, 0, 0, 0);
            acc1 = __builtin_amdgcn_mfma_f32_16x16x32_bf16(a, frg[dy + 1][dx], acc1, 0, 0, 0);
        }
        if (z == 0) {
            bf16x8 av0 = Avf[(ck * 2 + 0) * 64 + lane];
            bf16x8 av1 = Avf[(ck * 2 + 1) * 64 + lane];
            accv[0][0] = __builtin_amdgcn_mfma_f32_16x16x32_bf16(av0, frg[1][1], accv[0][0], 0, 0, 0);
            accv[0][1] = __builtin_amdgcn_mfma_f32_16x16x32_bf16(av0, frg[2][1], accv[0][1], 0, 0, 0);
            accv[1][0] = __builtin_amdgcn_mfma_f32_16x16x32_bf16(av1, frg[1][1], accv[1][0], 0, 0, 0);
            accv[1][1] = __builtin_amdgcn_mfma_f32_16x16x32_bf16(av1, frg[2][1], accv[1][1], 0, 0, 0);
        }
    }
#undef STAGE_EC

    float we[4], be[4];
    #pragma unroll
    for (int q = 0; q < 4; ++q) {
        int oc = z * 16 + 4 * g + q;
        we[q] = w_eh[oc];
        be[q] = b_ec[oc];
    }
    #pragma unroll
    for (int r = 0; r < 2; ++r) {
        const f32x4 accr = r ? acc1 : acc0;
        float p = 0.f;
        #pragma unroll
        for (int q = 0; q < 4; ++q)
            p += we[q] * fmaxf(accr[q] + be[q], 0.f);
        p += __shfl_xor(p, 16);
        p += __shfl_xor(p, 32);
        const int gpix = (ty0 + 2 * wv + r) * WC_ + tx0 + j;
        if (g == 0)
            eh4[((size_t)b * (HC_ * WC_) + gpix) * 4 + z] = p;
        if (z == 0) {
            unsigned short* cvp = cvb + ((size_t)b * (HC_ * WC_) + gpix) * 24;
            #pragma unroll
            for (int m = 0; m < 2; ++m)
                #pragma unroll
                for (int q = 0; q < 4; ++q) {
                    int ov = m * 16 + 4 * g + q;
                    if (ov < 20) cvp[ov] = f2bf(accv[m][r][q]);  // ov==19 = 0 (Avc padded)
                }
        }
    }
}

// ---------------- K_fine: fused fine stage (linearized q), 16x16 @256 ----------
__global__ __launch_bounds__(256, 4) void k_fine(
    const float* __restrict__ raw,
    const float* __restrict__ w_ef, const float* __restrict__ b_ef,
    const float* __restrict__ w_eh,
    const float* __restrict__ drv,           // 89 derived floats
    const float* __restrict__ eh4,           // (B,9216,4)
    const unsigned short* __restrict__ cvb,  // (B,9216,24) bf16
    float* __restrict__ out_y,
    float* __restrict__ out_ne)
{
    __shared__ float sRaw[3][20][20];          // 4.8 KB
    __shared__ unsigned short sV[324 * 26];    // 16.8 KB
    __shared__ float sNE[324];                 // 1.3 KB

    const int tid = threadIdx.x;
    const int b   = blockIdx.z;
    const int ty0 = blockIdx.y * 16;
    const int tx0 = blockIdx.x * 16;
    const float* rb = raw + (size_t)b * 3 * (HF_ * WF_);

    const float* Gm = drv;          // 9
    const float* uv = drv + 9;      // 3
    const float* Mm = drv + 13;     // [ci*19+ov]
    const float* bc = drv + 70;     // 19

    // Phase 0: stage raw 20x20x3 (zero-padded, 2-px halo)
    for (int i = tid; i < 1200; i += 256) {
        int ch = i / 400, rem = i - ch * 400;
        int ry = rem / 20, rx = rem - ry * 20;
        int gh = ty0 + ry - 2, gw = tx0 + rx - 2;
        float v = 0.f;
        if (gh >= 0 && gh < HF_ && gw >= 0 && gw < WF_)
            v = rb[(size_t)ch * (HF_ * WF_) + gh * WF_ + gw];
        sRaw[ch][ry][rx] = v;
    }
    __syncthreads();

    // Phase A: per halo pixel (18x18): ef -> ne ; v = bc + cv + M.r -> sV
    for (int p = tid; p < 324; p += 256) {
        const int iy = p / 18, ix = p - iy * 18;
        const int gh = ty0 + iy - 1, gw = tx0 + ix - 1;
        unsigned int* vw = (unsigned int*)&sV[p * 26];
        if (gh < 0 || gh >= HF_ || gw < 0 || gw >= WF_) {
            #pragma unroll
            for (int w = 0; w < 10; ++w) vw[w] = 0u;
            sNE[p] = 0.f;
            continue;
        }
        float ef = b_ef[0];
        #pragma unroll
        for (int ci = 0; ci < 3; ++ci)
            #pragma unroll
            for (int t = 0; t < 9; ++t)
                ef = fmaf(w_ef[ci * 9 + t], sRaw[ci][iy + t / 3][ix + t % 3], ef);
        ef = fmaxf(ef, 0.f);

        const int cpix = (gh >> 2) * WC_ + (gw >> 2);
        const float4 ehv = *(const float4*)(eh4 + ((size_t)b * (HC_ * WC_) + cpix) * 4);
        float logit = fmaf(w_eh[64], ef, (ehv.x + ehv.y) + (ehv.z + ehv.w));
        float ne = 1.f / (1.f + __expf(-logit));
        sNE[p] = ne;

        const float r0 = sRaw[0][iy + 1][ix + 1];
        const float r1 = sRaw[1][iy + 1][ix + 1];
        const float r2 = sRaw[2][iy + 1][ix + 1];

        float v[20];
        {
            const uint4* cvp = (const uint4*)(cvb + ((size_t)b * (HC_ * WC_) + cpix) * 24);
            uint4 a0 = cvp[0], a1 = cvp[1], a2 = cvp[2];
            unsigned int w10[10] = {a0.x, a0.y, a0.z, a0.w, a1.x, a1.y, a1.z, a1.w, a2.x, a2.y};
            #pragma unroll
            for (int o2 = 0; o2 < 10; ++o2) {
                v[2 * o2]     = bflo(w10[o2]);
                v[2 * o2 + 1] = bfhi(w10[o2]);
            }
        }
        #pragma unroll
        for (int ov = 0; ov < COUT_; ++ov)
            v[ov] = fmaf(Mm[38 + ov], r2,
                    fmaf(Mm[19 + ov], r1,
                    fmaf(Mm[ov], r0, v[ov] + bc[ov])));

        #pragma unroll
        for (int o2 = 0; o2 < 9; ++o2)
            vw[o2] = pk2(v[2 * o2], v[2 * o2 + 1]);
        vw[9] = (unsigned int)f2bf(v[18]);
    }
    __syncthreads();

    // Phase B: per own pixel — 3-dim score algebra, softmax, PV
    const int py = tid >> 4, px2 = tid & 15;
    const int iy = py + 1, ix = px2 + 1;
    const int pbase = iy * 18 + ix;

    float rn[3][9];
    #pragma unroll
    for (int ci = 0; ci < 3; ++ci)
        #pragma unroll
        for (int k = 0; k < 9; ++k)
            rn[ci][k] = sRaw[ci][iy + k / 3][ix + k % 3];

    const float rc0 = rn[0][4], rc1 = rn[1][4], rc2 = rn[2][4];
    const float h0 = fmaf(Gm[0], rc0, fmaf(Gm[1], rc1, fmaf(Gm[2], rc2, uv[0])));
    const float h1 = fmaf(Gm[3], rc0, fmaf(Gm[4], rc1, fmaf(Gm[5], rc2, uv[1])));
    const float h2 = fmaf(Gm[6], rc0, fmaf(Gm[7], rc1, fmaf(Gm[8], rc2, uv[2])));
    const float ac = fmaf(uv[0], rc0, fmaf(uv[1], rc1, fmaf(uv[2], rc2, drv[12])));

    float sc[9];
    #pragma unroll
    for (int k = 0; k < 9; ++k) {
        float d = fmaf(h0, rn[0][k], fmaf(h1, rn[1][k], fmaf(h2, rn[2][k], ac)));
        const int pn = pbase + (k / 3 - 1) * 18 + (k % 3 - 1);
        sc[k] = sNE[pn] * d;
    }
    float mmax = sc[0];
    #pragma unroll
    for (int k = 1; k < 9; ++k) mmax = fmaxf(mmax, sc[k]);
    float e[9];
    float ssum = 0.f;
    #pragma unroll
    for (int k = 0; k < 9; ++k) { e[k] = __expf(sc[k] - mmax); ssum += e[k]; }
    const float inv = 1.f / ssum;

    float y[COUT_];
    #pragma unroll
    for (int ov = 0; ov < COUT_; ++ov) y[ov] = 0.f;
    #pragma unroll
    for (int k = 0; k < 9; ++k) {
        const int pn = pbase + (k / 3 - 1) * 18 + (k % 3 - 1);
        const float a = e[k] * inv;
        const unsigned int* vp = (const unsigned int*)&sV[pn * 26];
        #pragma unroll
        for (int o2 = 0; o2 < 9; ++o2) {
            unsigned int u = vp[o2];
            y[2 * o2]     = fmaf(a, bflo(u), y[2 * o2]);
            y[2 * o2 + 1] = fmaf(a, bfhi(u), y[2 * o2 + 1]);
        }
        y[18] = fmaf(a, bflo(vp[9]), y[18]);
    }

    const int gh = ty0 + py, gw = tx0 + px2;
    const size_t ppos = (size_t)gh * WF_ + gw;
    #pragma unroll
    for (int ov = 0; ov < COUT_; ++ov)
        __builtin_nontemporal_store(y[ov], &out_y[((size_t)b * COUT_ + ov) * (HF_ * WF_) + ppos]);
    __builtin_nontemporal_store(sNE[pbase], &out_ne[(size_t)b * (HF_ * WF_) + ppos]);
}

// ---------------- launch ----------------
extern "C" void kernel_launch(void* const* d_in, const int* in_sizes, int n_in,
                              void* d_out, int out_size, void* d_ws, size_t ws_size,
                              hipStream_t stream)
{
    const float* coarse = (const float*)d_in[0];
    const float* raw    = (const float*)d_in[1];
    const float* w_ef   = (const float*)d_in[2];
    const float* b_ef   = (const float*)d_in[3];
    const float* w_ec   = (const float*)d_in[4];
    const float* b_ec   = (const float*)d_in[5];
    const float* w_eh   = (const float*)d_in[6];
    const float* w_q    = (const float*)d_in[7];
    const float* b_q    = (const float*)d_in[8];
    const float* w_v    = (const float*)d_in[9];
    const float* b_v    = (const float*)d_in[10];
    (void)in_sizes; (void)n_in; (void)out_size; (void)ws_size;

    unsigned char* ws = (unsigned char*)d_ws;
    size_t off = 0;
    uint4* Xt4            = (uint4*)(ws + off);          off += (size_t)B_ * 32 * 9604 * 16; // 9,834,496
    unsigned short* A_pk  = (unsigned short*)(ws + off); off += 294912;
    unsigned short* Avc   = (unsigned short*)(ws + off); off += 16384;
    float* eh4            = (float*)(ws + off);          off += (size_t)B_ * 9216 * 4 * 4;   // 294,912
    unsigned short* cvb   = (unsigned short*)(ws + off); off += (size_t)B_ * 9216 * 24 * 2;  // 884,736
    float* drv            = (float*)(ws + off);          off += 512;

    float* out_y  = (float*)d_out;
    float* out_ne = out_y + (size_t)B_ * COUT_ * HF_ * WF_;

    hipLaunchKernelGGL(k_pre, dim3(1157), dim3(256), 0, stream,
                       coarse, w_ec, w_v, w_q, b_q, b_v, Xt4, A_pk, Avc, drv);
    hipLaunchKernelGGL(k_ec, dim3(576), dim3(256), 0, stream,
                       Xt4, A_pk, Avc, b_ec, w_eh, eh4, cvb);
    hipLaunchKernelGGL(k_fine, dim3(24, 24, B_), dim3(256), 0, stream,
                       raw, w_ef, b_ef, w_eh, drv, eh4, cvb, out_y, out_ne);
}

// Round 17
// 44.158 us; speedup vs baseline: 3.4603x; 1.0012x over previous
//
#include <hip/hip_runtime.h>
#include <math.h>

#define B_    2
#define HC_   96
#define WC_   96
#define HF_   384
#define WF_   384
#define CINC_ 256
#define CH_   64
#define COUT_ 19

typedef __attribute__((ext_vector_type(8))) short bf16x8;
typedef __attribute__((ext_vector_type(4))) float f32x4;

__device__ __forceinline__ unsigned short f2bf(float f) {
    unsigned int u = __float_as_uint(f);
    u += 0x7fffu + ((u >> 16) & 1u);
    return (unsigned short)(u >> 16);
}
__device__ __forceinline__ unsigned int pk2(float a, float b) {
    return (unsigned int)f2bf(a) | ((unsigned int)f2bf(b) << 16);
}
__device__ __forceinline__ float bflo(unsigned int u) { return __uint_as_float(u << 16); }
__device__ __forceinline__ float bfhi(unsigned int u) { return __uint_as_float(u & 0xffff0000u); }

__device__ __forceinline__ void gl_lds16(const void* g, void* l) {
    __builtin_amdgcn_global_load_lds(
        (const __attribute__((address_space(1))) void*)g,
        (__attribute__((address_space(3))) void*)l, 16, 0, 0);
}

// Xt layout: [b][chunk32 = ck*4 + part][9604 halo px][8 ch] bf16 (uint4 granules)
#define XT_IDX(b, chunk, hpx)  (((size_t)((b) * 32 + (chunk))) * 9604 + (hpx))

// ---------------- K_pre ----------------
// bid 0-35   : weight prep (A_pk 16/thread, Avc 1/thread)
// bid 36-39  : zero 1-px border of Xt (all 32 chunks)
// bid 40-615 : transpose coarse f32 -> Xt (interior), 4 chunks/block
// bid 616    : derived weights drv[89]
__global__ __launch_bounds__(256) void k_pre(
    const float* __restrict__ x,      // coarse
    const float* __restrict__ w_ec, const float* __restrict__ w_v,
    const float* __restrict__ w_q,  const float* __restrict__ b_q,
    const float* __restrict__ b_v,
    uint4* __restrict__ Xt4,
    unsigned short* __restrict__ A_pk, unsigned short* __restrict__ Avc,
    float* __restrict__ drv)
{
    const int bid = blockIdx.x;
    const int tid = threadIdx.x;
    if (bid < 36) {
        int i0 = bid * 256 + tid;          // 0..9215
        #pragma unroll
        for (int k = 0; k < 16; ++k) {
            int i = i0 * 16 + k;           // 0..147455
            int e = i & 7, l = (i >> 3) & 63, m = (i >> 9) & 3, ck = (i >> 11) & 7, tap = i >> 14;
            int oc = m * 16 + (l & 15);
            int ch = ck * 32 + (l >> 4) * 8 + e;
            A_pk[i] = f2bf(w_ec[(oc * 256 + ch) * 9 + tap]);
        }
        if (i0 < 8192) {
            int i = i0;
            int e = i & 7, l = (i >> 3) & 63, m = (i >> 9) & 1, ck = (i >> 10) & 7;
            int ov = m * 16 + (l & 15);
            int ch = ck * 32 + (l >> 4) * 8 + e;
            Avc[i] = (ov < COUT_) ? f2bf(w_v[ov * 320 + ch]) : (unsigned short)0;
        }
        return;
    }
    if (bid < 40) {
        int e = (bid - 36) * 256 + tid;
        if (e >= 388 * B_) return;
        int b = e / 388, i = e - b * 388;
        int gy, gx;
        if (i < 98)       { gy = 0;           gx = i; }
        else if (i < 196) { gy = 97;          gx = i - 98; }
        else if (i < 292) { gy = i - 196 + 1; gx = 0; }
        else              { gy = i - 292 + 1; gx = 97; }
        const int hpx = gy * 98 + gx;
        uint4 zz; zz.x = zz.y = zz.z = zz.w = 0u;
        #pragma unroll
        for (int c = 0; c < 32; ++c) Xt4[XT_IDX(b, c, hpx)] = zz;
        return;
    }
    if (bid < 616) {
        int u = bid - 40;                  // 0..575
        int bx = u % 36;
        int v2 = u / 36;                   // 0..15
        int cg = v2 & 7;                   // chunk group (4 chunks each)
        int b  = v2 >> 3;
        int px = bx * 256 + tid;           // 0..9215
        int gy = px / 96, gx = px - gy * 96;
        const int hpx = (gy + 1) * 98 + gx + 1;
        const float* src = x + (size_t)b * CINC_ * 9216 + px;
        #pragma unroll
        for (int cc = 0; cc < 4; ++cc) {
            const int chunk = cg * 4 + cc;
            float f[8];
            #pragma unroll
            for (int t = 0; t < 8; ++t) f[t] = src[(size_t)(chunk * 8 + t) * 9216];
            uint4 v;
            v.x = pk2(f[0], f[1]);
            v.y = pk2(f[2], f[3]);
            v.z = pk2(f[4], f[5]);
            v.w = pk2(f[6], f[7]);
            Xt4[XT_IDX(b, chunk, hpx)] = v;   // coalesced: lanes -> consecutive px
        }
        return;
    }
    // derived weights
    {
        int i = tid;
        if (i < 9) {
            int ci = i / 3, cj = i % 3;
            float a = 0.f;
            for (int c = 0; c < 64; ++c) a += w_q[c * 3 + ci] * w_q[c * 3 + cj];
            drv[i] = a;
        } else if (i < 12) {
            int ci = i - 9;
            float a = 0.f;
            for (int c = 0; c < 64; ++c) a += w_q[c * 3 + ci] * b_q[c];
            drv[i] = a;
        } else if (i == 12) {
            float a = 0.f;
            for (int c = 0; c < 64; ++c) a += b_q[c] * b_q[c];
            drv[12] = a;
        } else if (i < 70) {
            int idx = i - 13, ci = idx / 19, ov = idx % 19;
            float a = 0.f;
            for (int c = 0; c < 64; ++c) a += w_v[ov * 320 + 256 + c] * w_q[c * 3 + ci];
            drv[i] = a;
        } else if (i < 89) {
            int ov = i - 70;
            float a = b_v[ov];
            for (int c = 0; c < 64; ++c) a += w_v[ov * 320 + 256 + c] * b_q[c];
            drv[i] = a;
        }
        return;
    }
}

// ---------------- K_ec: MFMA conv3x3 (16 oc quarter) + cv GEMM (z==0) ---------------
// 1D grid 576, XCD-affinity decode. T3/T4 pipeline: 4 LDS bufs, depth-2 prefetch,
// counted vmcnt + raw s_barrier (never drain-0 in loop). 3 blocks/CU resident.
__global__ __launch_bounds__(256, 3) void k_ec(
    const uint4* __restrict__ Xt4,
    const unsigned short* __restrict__ A_pk,
    const unsigned short* __restrict__ Avc,
    const float* __restrict__ b_ec, const float* __restrict__ w_eh,
    float* __restrict__ eh4,             // (B,9216,4) f32
    unsigned short* __restrict__ cvb)    // (B,9216,24) bf16
{
    __shared__ uint4 sB[4][768];   // 4 x 12 KB; slots [px*4 + swz(part)]

    const int tid  = threadIdx.x;
    const int lane = tid & 63;
    const int wv   = tid >> 6;
    const int j    = lane & 15;
    const int g    = lane >> 4;

    const int flat = blockIdx.x;          // 0..575
    const int xcd  = flat & 7;
    const int slot0 = flat >> 3;          // 0..71
    const int z    = slot0 & 3;
    const int t8   = slot0 >> 2;          // 0..17
    const int tile = t8 * 8 + xcd;        // 0..143
    const int b    = tile / 72;
    const int tl   = tile - b * 72;
    const int ty0  = (tl / 6) * 8;
    const int tx0  = (tl % 6) * 16;

    f32x4 acc0 = (f32x4)0.f, acc1 = (f32x4)0.f;
    f32x4 accv[2][2];
    accv[0][0] = accv[0][1] = accv[1][0] = accv[1][1] = (f32x4)0.f;

    const bf16x8* Af  = (const bf16x8*)A_pk;
    const bf16x8* Avf = (const bf16x8*)Avc;

#define STAGE_EC(BUF, CK)                                                      \
    {                                                                          \
        _Pragma("unroll")                                                      \
        for (int rr = 0; rr < 3; ++rr) {                                       \
            int slot = 192 * wv + 64 * rr + lane;                              \
            int px = slot >> 2;                                                \
            px = px > 179 ? 179 : px;                                          \
            int part = (slot & 3) ^ ((px >> 1) & 3);                           \
            int row = px / 18, col = px - row * 18;                            \
            const uint4* src = Xt4 + XT_IDX(b, (CK) * 4 + part,                \
                                            (ty0 + row) * 98 + (tx0 + col));   \
            gl_lds16(src, &sB[BUF][192 * wv + 64 * rr]);                       \
        }                                                                      \
    }

    STAGE_EC(0, 0);
    STAGE_EC(1, 1);

    #pragma unroll
    for (int ck = 0; ck < 8; ++ck) {
        if (ck < 6) STAGE_EC((ck + 2) & 3, ck + 2);

        if (ck < 6)       asm volatile("s_waitcnt vmcnt(6)" ::: "memory");
        else if (ck == 6) asm volatile("s_waitcnt vmcnt(3)" ::: "memory");
        else              asm volatile("s_waitcnt vmcnt(0)" ::: "memory");
        __builtin_amdgcn_sched_barrier(0);
        asm volatile("s_barrier" ::: "memory");

        const int cur = ck & 3;
        bf16x8 frg[4][3];
        #pragma unroll
        for (int rr = 0; rr < 4; ++rr)
            #pragma unroll
            for (int dx = 0; dx < 3; ++dx) {
                int px = (2 * wv + rr) * 18 + j + dx;
                int slot = (px << 2) + (g ^ ((px >> 1) & 3));
                frg[rr][dx] = *(const bf16x8*)&sB[cur][slot];
            }

        #pragma unroll
        for (int tap = 0; tap < 9; ++tap) {
            const int dy = tap / 3, dx = tap % 3;
            bf16x8 a = Af[((tap * 8 + ck) * 4 + z) * 64 + lane];
            acc0 = __builtin_amdgcn_mfma_f32_16x16x32_bf16(a, frg[dy][dx], acc0, 0, 0, 0);
            acc1 = __builtin_amdgcn_mfma_f32_16x16x32_bf16(a, frg[dy + 1][dx], acc1, 0, 0, 0);
        }
        if (z == 0) {
            bf16x8 av0 = Avf[(ck * 2 + 0) * 64 + lane];
            bf16x8 av1 = Avf[(ck * 2 + 1) * 64 + lane];
            accv[0][0] = __builtin_amdgcn_mfma_f32_16x16x32_bf16(av0, frg[1][1], accv[0][0], 0, 0, 0);
            accv[0][1] = __builtin_amdgcn_mfma_f32_16x16x32_bf16(av0, frg[2][1], accv[0][1], 0, 0, 0);
            accv[1][0] = __builtin_amdgcn_mfma_f32_16x16x32_bf16(av1, frg[1][1], accv[1][0], 0, 0, 0);
            accv[1][1] = __builtin_amdgcn_mfma_f32_16x16x32_bf16(av1, frg[2][1], accv[1][1], 0, 0, 0);
        }
    }
#undef STAGE_EC

    float we[4], be[4];
    #pragma unroll
    for (int q = 0; q < 4; ++q) {
        int oc = z * 16 + 4 * g + q;
        we[q] = w_eh[oc];
        be[q] = b_ec[oc];
    }
    #pragma unroll
    for (int r = 0; r < 2; ++r) {
        const f32x4 accr = r ? acc1 : acc0;
        float p = 0.f;
        #pragma unroll
        for (int q = 0; q < 4; ++q)
            p += we[q] * fmaxf(accr[q] + be[q], 0.f);
        p += __shfl_xor(p, 16);
        p += __shfl_xor(p, 32);
        const int gpix = (ty0 + 2 * wv + r) * WC_ + tx0 + j;
        if (g == 0)
            eh4[((size_t)b * (HC_ * WC_) + gpix) * 4 + z] = p;
        if (z == 0) {
            unsigned short* cvp = cvb + ((size_t)b * (HC_ * WC_) + gpix) * 24;
            #pragma unroll
            for (int m = 0; m < 2; ++m)
                #pragma unroll
                for (int q = 0; q < 4; ++q) {
                    int ov = m * 16 + 4 * g + q;
                    if (ov < 20) cvp[ov] = f2bf(accv[m][r][q]);  // ov==19 = 0 (Avc padded)
                }
        }
    }
}

// ---------------- K_fine: fused fine stage (linearized q), 16x16 @256 ----------
__global__ __launch_bounds__(256, 6) void k_fine(
    const float* __restrict__ raw,
    const float* __restrict__ w_ef, const float* __restrict__ b_ef,
    const float* __restrict__ w_eh,
    const float* __restrict__ drv,           // 89 derived floats
    const float* __restrict__ eh4,           // (B,9216,4)
    const unsigned short* __restrict__ cvb,  // (B,9216,24) bf16
    float* __restrict__ out_y,
    float* __restrict__ out_ne)
{
    __shared__ float sRaw[3][20][20];          // 4.8 KB
    __shared__ unsigned short sV[324 * 26];    // 16.8 KB
    __shared__ float sNE[324];                 // 1.3 KB

    const int tid = threadIdx.x;
    const int b   = blockIdx.z;
    const int ty0 = blockIdx.y * 16;
    const int tx0 = blockIdx.x * 16;
    const float* rb = raw + (size_t)b * 3 * (HF_ * WF_);

    const float* Gm = drv;          // 9
    const float* uv = drv + 9;      // 3
    const float* Mm = drv + 13;     // [ci*19+ov]
    const float* bc = drv + 70;     // 19

    // Phase 0: stage raw 20x20x3 (zero-padded, 2-px halo)
    for (int i = tid; i < 1200; i += 256) {
        int ch = i / 400, rem = i - ch * 400;
        int ry = rem / 20, rx = rem - ry * 20;
        int gh = ty0 + ry - 2, gw = tx0 + rx - 2;
        float v = 0.f;
        if (gh >= 0 && gh < HF_ && gw >= 0 && gw < WF_)
            v = rb[(size_t)ch * (HF_ * WF_) + gh * WF_ + gw];
        sRaw[ch][ry][rx] = v;
    }
    __syncthreads();

    // Phase A: per halo pixel (18x18): ef -> ne ; v = bc + cv + M.r -> sV
    for (int p = tid; p < 324; p += 256) {
        const int iy = p / 18, ix = p - iy * 18;
        const int gh = ty0 + iy - 1, gw = tx0 + ix - 1;
        unsigned int* vw = (unsigned int*)&sV[p * 26];
        if (gh < 0 || gh >= HF_ || gw < 0 || gw >= WF_) {
            #pragma unroll
            for (int w = 0; w < 10; ++w) vw[w] = 0u;
            sNE[p] = 0.f;
            continue;
        }
        float ef = b_ef[0];
        #pragma unroll
        for (int ci = 0; ci < 3; ++ci)
            #pragma unroll
            for (int t = 0; t < 9; ++t)
                ef = fmaf(w_ef[ci * 9 + t], sRaw[ci][iy + t / 3][ix + t % 3], ef);
        ef = fmaxf(ef, 0.f);

        const int cpix = (gh >> 2) * WC_ + (gw >> 2);
        const float4 ehv = *(const float4*)(eh4 + ((size_t)b * (HC_ * WC_) + cpix) * 4);
        float logit = fmaf(w_eh[64], ef, (ehv.x + ehv.y) + (ehv.z + ehv.w));
        float ne = 1.f / (1.f + __expf(-logit));
        sNE[p] = ne;

        const float r0 = sRaw[0][iy + 1][ix + 1];
        const float r1 = sRaw[1][iy + 1][ix + 1];
        const float r2 = sRaw[2][iy + 1][ix + 1];

        float v[20];
        {
            const uint4* cvp = (const uint4*)(cvb + ((size_t)b * (HC_ * WC_) + cpix) * 24);
            uint4 a0 = cvp[0], a1 = cvp[1], a2 = cvp[2];
            unsigned int w10[10] = {a0.x, a0.y, a0.z, a0.w, a1.x, a1.y, a1.z, a1.w, a2.x, a2.y};
            #pragma unroll
            for (int o2 = 0; o2 < 10; ++o2) {
                v[2 * o2]     = bflo(w10[o2]);
                v[2 * o2 + 1] = bfhi(w10[o2]);
            }
        }
        #pragma unroll
        for (int ov = 0; ov < COUT_; ++ov)
            v[ov] = fmaf(Mm[38 + ov], r2,
                    fmaf(Mm[19 + ov], r1,
                    fmaf(Mm[ov], r0, v[ov] + bc[ov])));

        #pragma unroll
        for (int o2 = 0; o2 < 9; ++o2)
            vw[o2] = pk2(v[2 * o2], v[2 * o2 + 1]);
        vw[9] = (unsigned int)f2bf(v[18]);
    }
    __syncthreads();

    // Phase B: per own pixel — 3-dim score algebra, softmax, PV
    const int py = tid >> 4, px2 = tid & 15;
    const int iy = py + 1, ix = px2 + 1;
    const int pbase = iy * 18 + ix;

    float rn[3][9];
    #pragma unroll
    for (int ci = 0; ci < 3; ++ci)
        #pragma unroll
        for (int k = 0; k < 9; ++k)
            rn[ci][k] = sRaw[ci][iy + k / 3][ix + k % 3];

    const float rc0 = rn[0][4], rc1 = rn[1][4], rc2 = rn[2][4];
    const float h0 = fmaf(Gm[0], rc0, fmaf(Gm[1], rc1, fmaf(Gm[2], rc2, uv[0])));
    const float h1 = fmaf(Gm[3], rc0, fmaf(Gm[4], rc1, fmaf(Gm[5], rc2, uv[1])));
    const float h2 = fmaf(Gm[6], rc0, fmaf(Gm[7], rc1, fmaf(Gm[8], rc2, uv[2])));
    const float ac = fmaf(uv[0], rc0, fmaf(uv[1], rc1, fmaf(uv[2], rc2, drv[12])));

    float sc[9];
    #pragma unroll
    for (int k = 0; k < 9; ++k) {
        float d = fmaf(h0, rn[0][k], fmaf(h1, rn[1][k], fmaf(h2, rn[2][k], ac)));
        const int pn = pbase + (k / 3 - 1) * 18 + (k % 3 - 1);
        sc[k] = sNE[pn] * d;
    }
    float mmax = sc[0];
    #pragma unroll
    for (int k = 1; k < 9; ++k) mmax = fmaxf(mmax, sc[k]);
    float e[9];
    float ssum = 0.f;
    #pragma unroll
    for (int k = 0; k < 9; ++k) { e[k] = __expf(sc[k] - mmax); ssum += e[k]; }
    const float inv = 1.f / ssum;

    float y[COUT_];
    #pragma unroll
    for (int ov = 0; ov < COUT_; ++ov) y[ov] = 0.f;
    #pragma unroll
    for (int k = 0; k < 9; ++k) {
        const int pn = pbase + (k / 3 - 1) * 18 + (k % 3 - 1);
        const float a = e[k] * inv;
        const unsigned int* vp = (const unsigned int*)&sV[pn * 26];
        #pragma unroll
        for (int o2 = 0; o2 < 9; ++o2) {
            unsigned int u = vp[o2];
            y[2 * o2]     = fmaf(a, bflo(u), y[2 * o2]);
            y[2 * o2 + 1] = fmaf(a, bfhi(u), y[2 * o2 + 1]);
        }
        y[18] = fmaf(a, bflo(vp[9]), y[18]);
    }

    const int gh = ty0 + py, gw = tx0 + px2;
    const size_t ppos = (size_t)gh * WF_ + gw;
    #pragma unroll
    for (int ov = 0; ov < COUT_; ++ov)
        __builtin_nontemporal_store(y[ov], &out_y[((size_t)b * COUT_ + ov) * (HF_ * WF_) + ppos]);
    __builtin_nontemporal_store(sNE[pbase], &out_ne[(size_t)b * (HF_ * WF_) + ppos]);
}

// ---------------- launch ----------------
extern "C" void kernel_launch(void* const* d_in, const int* in_sizes, int n_in,
                              void* d_out, int out_size, void* d_ws, size_t ws_size,
                              hipStream_t stream)
{
    const float* coarse = (const float*)d_in[0];
    const float* raw    = (const float*)d_in[1];
    const float* w_ef   = (const float*)d_in[2];
    const float* b_ef   = (const float*)d_in[3];
    const float* w_ec   = (const float*)d_in[4];
    const float* b_ec   = (const float*)d_in[5];
    const float* w_eh   = (const float*)d_in[6];
    const float* w_q    = (const float*)d_in[7];
    const float* b_q    = (const float*)d_in[8];
    const float* w_v    = (const float*)d_in[9];
    const float* b_v    = (const float*)d_in[10];
    (void)in_sizes; (void)n_in; (void)out_size; (void)ws_size;

    unsigned char* ws = (unsigned char*)d_ws;
    size_t off = 0;
    uint4* Xt4            = (uint4*)(ws + off);          off += (size_t)B_ * 32 * 9604 * 16; // 9,834,496
    unsigned short* A_pk  = (unsigned short*)(ws + off); off += 294912;
    unsigned short* Avc   = (unsigned short*)(ws + off); off += 16384;
    float* eh4            = (float*)(ws + off);          off += (size_t)B_ * 9216 * 4 * 4;   // 294,912
    unsigned short* cvb   = (unsigned short*)(ws + off); off += (size_t)B_ * 9216 * 24 * 2;  // 884,736
    float* drv            = (float*)(ws + off);          off += 512;

    float* out_y  = (float*)d_out;
    float* out_ne = out_y + (size_t)B_ * COUT_ * HF_ * WF_;

    hipLaunchKernelGGL(k_pre, dim3(617), dim3(256), 0, stream,
                       coarse, w_ec, w_v, w_q, b_q, b_v, Xt4, A_pk, Avc, drv);
    hipLaunchKernelGGL(k_ec, dim3(576), dim3(256), 0, stream,
                       Xt4, A_pk, Avc, b_ec, w_eh, eh4, cvb);
    hipLaunchKernelGGL(k_fine, dim3(24, 24, B_), dim3(256), 0, stream,
                       raw, w_ef, b_ef, w_eh, drv, eh4, cvb, out_y, out_ne);
}